// Round 1
// baseline (1332.136 us; speedup 1.0000x reference)
//
#include <hip/hip_runtime.h>
#include <cmath>

#define L_SEQ 2048
#define DM 512
#define DI 1024      // D_INNER
#define DS 16        // D_STATE
#define NSP 1056     // DI + 2*DS
#define NC 32        // scan chunks
#define CL 64        // chunk length (NC*CL == L_SEQ)

__device__ __forceinline__ float sigm(float x) { return 1.0f / (1.0f + __expf(-x)); }

// C[M,N] = op(A)[M,K] @ W[K,N] + bias ; epi: 0 = none, 1 = softplus
// revA: read A rows reversed; revC: write C rows reversed.
__global__ __launch_bounds__(256) void gemm_k(
    const float* __restrict__ A, int lda, int revA,
    const float* __restrict__ W,
    const float* __restrict__ bias,
    float* __restrict__ C, int ldc, int revC,
    int M, int N, int K, int epi)
{
    __shared__ float As[16][65];
    __shared__ float Ws[16][65];
    const int tid = threadIdx.x;
    const int bm = blockIdx.y * 64;
    const int bn = blockIdx.x * 64;
    const int tx = tid & 15;
    const int ty = tid >> 4;
    float acc[4][4] = {};

    for (int k0 = 0; k0 < K; k0 += 16) {
        // A tile: 64 rows x 16 k
        #pragma unroll
        for (int p = 0; p < 4; ++p) {
            int m = ty + p * 16;
            int row = bm + m;
            int ar = revA ? (M - 1 - row) : row;
            As[tx][m] = A[(size_t)ar * lda + k0 + tx];
        }
        // W tile: 16 k x 64 n
        #pragma unroll
        for (int p = 0; p < 4; ++p) {
            int n = tid & 63;
            int kk = (tid >> 6) + p * 4;
            int gn = bn + n;
            Ws[kk][n] = (gn < N) ? W[(size_t)(k0 + kk) * N + gn] : 0.0f;
        }
        __syncthreads();
        #pragma unroll
        for (int kk = 0; kk < 16; ++kk) {
            float a[4], b[4];
            #pragma unroll
            for (int i = 0; i < 4; ++i) a[i] = As[kk][ty * 4 + i];
            #pragma unroll
            for (int j = 0; j < 4; ++j) b[j] = Ws[kk][tx * 4 + j];
            #pragma unroll
            for (int i = 0; i < 4; ++i)
                #pragma unroll
                for (int j = 0; j < 4; ++j)
                    acc[i][j] += a[i] * b[j];
        }
        __syncthreads();
    }

    #pragma unroll
    for (int i = 0; i < 4; ++i) {
        int row = bm + ty * 4 + i;
        int orow = revC ? (M - 1 - row) : row;
        #pragma unroll
        for (int j = 0; j < 4; ++j) {
            int gn = bn + tx * 4 + j;
            if (gn < N) {
                float v = acc[i][j] + bias[gn];
                if (epi == 1) v = (v > 20.0f) ? v : log1pf(__expf(v));
                C[(size_t)orow * ldc + gn] = v;
            }
        }
    }
}

// causal depthwise conv over x_ssm part of XZ (cols 0..DI-1); writes conv out + silu(conv out)
__global__ __launch_bounds__(256) void conv_k(
    const float* __restrict__ XZ, const float* __restrict__ cw,
    const float* __restrict__ cb, float* __restrict__ XC, float* __restrict__ SC)
{
    int idx = blockIdx.x * 256 + threadIdx.x;  // l*DI + d
    int d = idx & (DI - 1);
    int l = idx >> 10;
    float w0 = cw[d * 4 + 0], w1 = cw[d * 4 + 1], w2 = cw[d * 4 + 2], w3 = cw[d * 4 + 3];
    float acc = cb[d];
    if (l >= 3) acc += XZ[(size_t)(l - 3) * (2 * DI) + d] * w0;
    if (l >= 2) acc += XZ[(size_t)(l - 2) * (2 * DI) + d] * w1;
    if (l >= 1) acc += XZ[(size_t)(l - 1) * (2 * DI) + d] * w2;
    acc += XZ[(size_t)l * (2 * DI) + d] * w3;
    XC[idx] = acc;
    SC[idx] = acc * sigm(acc);
}

// Phase A: per (dir, chunk, d) compute prod(dA) and local h (from h=0) over the chunk
__global__ __launch_bounds__(256) void scanA_k(
    const float* __restrict__ DT, const float* __restrict__ XC,
    const float* __restrict__ SP, const float* __restrict__ Alog,
    float* __restrict__ Pend, float* __restrict__ Hl)
{
    __shared__ float Bsh[CL][DS];
    int dir = blockIdx.z;
    int c = blockIdx.y;
    int d = blockIdx.x * 256 + threadIdx.x;
    DT += (size_t)dir * L_SEQ * DI;
    XC += (size_t)dir * L_SEQ * DI;
    SP += (size_t)dir * L_SEQ * NSP;
    int l0 = c * CL;
    for (int i = threadIdx.x; i < CL * DS; i += 256) {
        int ll = i >> 4, ss = i & 15;
        Bsh[ll][ss] = SP[(size_t)(l0 + ll) * NSP + DI + ss];
    }
    __syncthreads();
    float Ae[DS], h[DS], P[DS];
    #pragma unroll
    for (int s = 0; s < DS; ++s) { Ae[s] = -__expf(Alog[d * DS + s]); h[s] = 0.f; P[s] = 1.f; }
    for (int t = 0; t < CL; ++t) {
        int l = l0 + t;
        float dt = DT[(size_t)l * DI + d];
        float xv = XC[(size_t)l * DI + d];
        float dtx = dt * xv;
        #pragma unroll
        for (int s = 0; s < DS; ++s) {
            float e = __expf(dt * Ae[s]);
            h[s] = e * h[s] + dtx * Bsh[t][s];
            P[s] *= e;
        }
    }
    size_t o = ((size_t)(dir * NC + c) * DI + d) * DS;
    #pragma unroll
    for (int s = 0; s < DS; ++s) { Pend[o + s] = P[s]; Hl[o + s] = h[s]; }
}

// Phase B: sequentially combine chunk summaries -> true chunk-start states
__global__ __launch_bounds__(256) void scanB_k(
    const float* __restrict__ Pend, const float* __restrict__ Hl, float* __restrict__ Hs)
{
    int idx = blockIdx.x * 256 + threadIdx.x;  // dir*DI*DS + d*DS + s  (2*16384 total)
    int dir = idx >> 14;
    int ds = idx & 16383;
    float h = 0.f;
    for (int c = 0; c < NC; ++c) {
        size_t o = ((size_t)(dir * NC + c)) * (DI * DS) + ds;
        Hs[o] = h;
        h = Pend[o] * h + Hl[o];
    }
}

// Phase C: recompute within chunk from true start; fuse y = sum_s h*C + Dp*x and silu(z) gate
__global__ __launch_bounds__(256) void scanC_k(
    const float* __restrict__ DT, const float* __restrict__ XC,
    const float* __restrict__ SP, const float* __restrict__ XZ,
    const float* __restrict__ Alog, const float* __restrict__ Dp,
    const float* __restrict__ Hs, float* __restrict__ G)
{
    __shared__ float Bsh[CL][DS];
    __shared__ float Csh[CL][DS];
    int dir = blockIdx.z;
    int c = blockIdx.y;
    int d = blockIdx.x * 256 + threadIdx.x;
    DT += (size_t)dir * L_SEQ * DI;
    XC += (size_t)dir * L_SEQ * DI;
    SP += (size_t)dir * L_SEQ * NSP;
    XZ += (size_t)dir * L_SEQ * (2 * DI);
    G  += (size_t)dir * L_SEQ * DI;
    int l0 = c * CL;
    for (int i = threadIdx.x; i < CL * DS; i += 256) {
        int ll = i >> 4, ss = i & 15;
        size_t base = (size_t)(l0 + ll) * NSP + DI;
        Bsh[ll][ss] = SP[base + ss];
        Csh[ll][ss] = SP[base + DS + ss];
    }
    __syncthreads();
    float Ae[DS], h[DS];
    size_t o = ((size_t)(dir * NC + c) * DI + d) * DS;
    #pragma unroll
    for (int s = 0; s < DS; ++s) { Ae[s] = -__expf(Alog[d * DS + s]); h[s] = Hs[o + s]; }
    float dpv = Dp[d];
    for (int t = 0; t < CL; ++t) {
        int l = l0 + t;
        float dt = DT[(size_t)l * DI + d];
        float xv = XC[(size_t)l * DI + d];
        float dtx = dt * xv;
        float y = 0.f;
        #pragma unroll
        for (int s = 0; s < DS; ++s) {
            float e = __expf(dt * Ae[s]);
            h[s] = e * h[s] + dtx * Bsh[t][s];
            y += h[s] * Csh[t][s];
        }
        y += dpv * xv;
        float z = XZ[(size_t)l * (2 * DI) + DI + d];
        G[(size_t)l * DI + d] = y * (z * sigm(z));
    }
}

extern "C" void kernel_launch(void* const* d_in, const int* in_sizes, int n_in,
                              void* d_out, int out_size, void* d_ws, size_t ws_size,
                              hipStream_t stream)
{
    (void)in_sizes; (void)n_in; (void)out_size; (void)ws_size;
    const float* x = (const float*)d_in[0];
    const float* inW[2]  = {(const float*)d_in[1],  (const float*)d_in[11]};
    const float* inb[2]  = {(const float*)d_in[2],  (const float*)d_in[12]};
    const float* cw[2]   = {(const float*)d_in[3],  (const float*)d_in[13]};
    const float* cb[2]   = {(const float*)d_in[4],  (const float*)d_in[14]};
    const float* xpW[2]  = {(const float*)d_in[5],  (const float*)d_in[15]};
    const float* xpb[2]  = {(const float*)d_in[6],  (const float*)d_in[16]};
    const float* dtW[2]  = {(const float*)d_in[7],  (const float*)d_in[17]};
    const float* dtb[2]  = {(const float*)d_in[8],  (const float*)d_in[18]};
    const float* outW[2] = {(const float*)d_in[9],  (const float*)d_in[19]};
    const float* outb[2] = {(const float*)d_in[10], (const float*)d_in[20]};
    const float* Alog = (const float*)d_in[21];
    const float* Dp   = (const float*)d_in[22];
    const float* fuW  = (const float*)d_in[23];
    const float* fub  = (const float*)d_in[24];
    float* out = (float*)d_out;

    float* ws = (float*)d_ws;
    size_t off = 0;
    auto alloc = [&](size_t n) { float* p = ws + off; off += n; return p; };
    float* XZ  = alloc((size_t)2 * L_SEQ * 2 * DI);   // per dir: L x 2048 (x_ssm | z)
    float* XC  = alloc((size_t)2 * L_SEQ * DI);       // conv output
    float* SC  = alloc((size_t)2 * L_SEQ * DI);       // silu(conv output)
    float* SP  = alloc((size_t)2 * L_SEQ * NSP);      // delta | B | C
    float* DTb = alloc((size_t)2 * L_SEQ * DI);       // softplus dt
    float* Pend= alloc((size_t)2 * NC * DI * DS);
    float* Hl  = alloc((size_t)2 * NC * DI * DS);
    float* Hs  = alloc((size_t)2 * NC * DI * DS);
    float* G   = alloc((size_t)2 * L_SEQ * DI);       // y * silu(z)
    float* OC  = alloc((size_t)L_SEQ * DI);           // concat(out_fwd, out_bwd)

    dim3 blk(256);
    // 1) input projection (bwd reads x reversed)
    for (int dir = 0; dir < 2; ++dir)
        gemm_k<<<dim3(32, 32), blk, 0, stream>>>(
            x, DM, dir, inW[dir], inb[dir],
            XZ + (size_t)dir * L_SEQ * 2 * DI, 2 * DI, 0,
            L_SEQ, 2 * DI, DM, 0);
    // 2) causal depthwise conv + silu
    for (int dir = 0; dir < 2; ++dir)
        conv_k<<<dim3(L_SEQ * DI / 256), blk, 0, stream>>>(
            XZ + (size_t)dir * L_SEQ * 2 * DI, cw[dir], cb[dir],
            XC + (size_t)dir * L_SEQ * DI, SC + (size_t)dir * L_SEQ * DI);
    // 3) x-projection: sp = silu(conv) @ xp_W + xp_b
    for (int dir = 0; dir < 2; ++dir)
        gemm_k<<<dim3((NSP + 63) / 64, 32), blk, 0, stream>>>(
            SC + (size_t)dir * L_SEQ * DI, DI, 0, xpW[dir], xpb[dir],
            SP + (size_t)dir * L_SEQ * NSP, NSP, 0,
            L_SEQ, NSP, DI, 0);
    // 4) dt = softplus(delta @ dt_W + dt_b)
    for (int dir = 0; dir < 2; ++dir)
        gemm_k<<<dim3(16, 32), blk, 0, stream>>>(
            SP + (size_t)dir * L_SEQ * NSP, NSP, 0, dtW[dir], dtb[dir],
            DTb + (size_t)dir * L_SEQ * DI, DI, 0,
            L_SEQ, DI, DI, 1);
    // 5) chunked selective scan
    scanA_k<<<dim3(DI / 256, NC, 2), blk, 0, stream>>>(DTb, XC, SP, Alog, Pend, Hl);
    scanB_k<<<dim3(2 * DI * DS / 256), blk, 0, stream>>>(Pend, Hl, Hs);
    scanC_k<<<dim3(DI / 256, NC, 2), blk, 0, stream>>>(DTb, XC, SP, XZ, Alog, Dp, Hs, G);
    // 6) out projection into concat buffer (bwd rows reversed back)
    for (int dir = 0; dir < 2; ++dir)
        gemm_k<<<dim3(8, 32), blk, 0, stream>>>(
            G + (size_t)dir * L_SEQ * DI, DI, 0, outW[dir], outb[dir],
            OC + (size_t)dir * DM, DI, (dir == 1) ? 1 : 0,
            L_SEQ, DM, DI, 0);
    // 7) fusion GEMM -> final output
    gemm_k<<<dim3(8, 32), blk, 0, stream>>>(
        OC, DI, 0, fuW, fub,
        out, DM, 0,
        L_SEQ, DM, DI, 0);
}

// Round 2
// 623.128 us; speedup vs baseline: 2.1378x; 2.1378x over previous
//
#include <hip/hip_runtime.h>
#include <cmath>

#define L_SEQ 2048
#define DM 512
#define DI 1024      // D_INNER
#define DS 16        // D_STATE
#define NSP 1056     // DI + 2*DS
#define NC 32        // scan chunks
#define CL 64        // chunk length (NC*CL == L_SEQ)

typedef unsigned short ushortT;
typedef __attribute__((ext_vector_type(8))) short short8;
typedef __attribute__((ext_vector_type(4))) float float4_t;

__device__ __forceinline__ float sigm(float x) { return 1.0f / (1.0f + __expf(-x)); }

__device__ __forceinline__ ushortT f2bf(float f) {
    unsigned u = __float_as_uint(f);
    unsigned r = u + 0x7FFFu + ((u >> 16) & 1u);
    return (ushortT)(r >> 16);
}

// ---- weight convert + transpose: W[K][N] fp32 -> Wt[N][K] bf16 ----
__global__ __launch_bounds__(256) void wcvt_k(const float* __restrict__ W,
                                              ushortT* __restrict__ Wt,
                                              int K, int N)
{
    __shared__ ushortT t[32][33];
    int n0 = blockIdx.x * 32, k0 = blockIdx.y * 32;
    int tx = threadIdx.x & 31, ty = threadIdx.x >> 5;   // 32 x 8
    #pragma unroll
    for (int i = 0; i < 32; i += 8)
        t[ty + i][tx] = f2bf(W[(size_t)(k0 + ty + i) * N + n0 + tx]);
    __syncthreads();
    #pragma unroll
    for (int i = 0; i < 32; i += 8)
        Wt[(size_t)(n0 + ty + i) * K + k0 + tx] = t[tx][ty + i];
}

// ---- bf16 MFMA GEMM: C[M,N] = op(A_fp32)[M,K] @ Wt_bf16^T + bias ----
// Wt layout: [N][K] bf16. A converted fp32->bf16 during staging.
// epi: 0 none, 1 softplus. revA/revC: row reversal on read/write.
__global__ __launch_bounds__(256) void gemm_mfma(
    const float* __restrict__ A, int lda, int revA,
    const ushortT* __restrict__ Wt,
    const float* __restrict__ bias,
    float* __restrict__ C, int ldc, int revC,
    int M, int N, int K, int epi)
{
    __shared__ ushortT As[128 * 40];   // stride 40 bf16 (80B = 20 banks: conflict-free-ish)
    __shared__ ushortT Bs[128 * 40];
    const int tid  = threadIdx.x;
    const int bm   = blockIdx.y * 128;
    const int bn   = blockIdx.x * 128;
    const int wave = tid >> 6;
    const int lane = tid & 63;
    const int quad = lane >> 4;
    const int r    = lane & 15;
    const int wm   = (wave >> 1) * 64;
    const int wn   = (wave & 1) * 64;

    // staging roles: 2 threads per row, each covers 16 k
    const int srow  = tid >> 1;
    const int shalf = tid & 1;

    float4_t acc[4][4];
    #pragma unroll
    for (int i = 0; i < 4; ++i)
        #pragma unroll
        for (int j = 0; j < 4; ++j)
            acc[i][j] = (float4_t){0.f, 0.f, 0.f, 0.f};

    int arow = bm + srow;
    if (revA) arow = M - 1 - arow;
    const float* Aptr = A + (size_t)arow * lda + shalf * 16;
    const int brow = bn + srow;            // n index of Wt
    const bool bvalid = brow < N;
    const ushortT* Bptr = Wt + (size_t)(bvalid ? brow : 0) * K + shalf * 16;
    ushortT* AsW = As + srow * 40 + shalf * 16;
    ushortT* BsW = Bs + srow * 40 + shalf * 16;

    for (int k0 = 0; k0 < K; k0 += 32) {
        // stage A: 16 fp32 -> 16 bf16
        float4_t a0 = *(const float4_t*)(Aptr + k0);
        float4_t a1 = *(const float4_t*)(Aptr + k0 + 4);
        float4_t a2 = *(const float4_t*)(Aptr + k0 + 8);
        float4_t a3 = *(const float4_t*)(Aptr + k0 + 12);
        short8 ua, ub;
        ua[0] = (short)f2bf(a0[0]); ua[1] = (short)f2bf(a0[1]);
        ua[2] = (short)f2bf(a0[2]); ua[3] = (short)f2bf(a0[3]);
        ua[4] = (short)f2bf(a1[0]); ua[5] = (short)f2bf(a1[1]);
        ua[6] = (short)f2bf(a1[2]); ua[7] = (short)f2bf(a1[3]);
        ub[0] = (short)f2bf(a2[0]); ub[1] = (short)f2bf(a2[1]);
        ub[2] = (short)f2bf(a2[2]); ub[3] = (short)f2bf(a2[3]);
        ub[4] = (short)f2bf(a3[0]); ub[5] = (short)f2bf(a3[1]);
        ub[6] = (short)f2bf(a3[2]); ub[7] = (short)f2bf(a3[3]);
        *(short8*)(AsW)     = ua;
        *(short8*)(AsW + 8) = ub;
        // stage B (already bf16, pre-transposed)
        short8 w0 = {0,0,0,0,0,0,0,0}, w1 = {0,0,0,0,0,0,0,0};
        if (bvalid) {
            w0 = *(const short8*)(Bptr + k0);
            w1 = *(const short8*)(Bptr + k0 + 8);
        }
        *(short8*)(BsW)     = w0;
        *(short8*)(BsW + 8) = w1;
        __syncthreads();

        short8 af[4], bfr[4];
        #pragma unroll
        for (int mi = 0; mi < 4; ++mi)
            af[mi] = *(const short8*)&As[(wm + mi * 16 + r) * 40 + quad * 8];
        #pragma unroll
        for (int ni = 0; ni < 4; ++ni)
            bfr[ni] = *(const short8*)&Bs[(wn + ni * 16 + r) * 40 + quad * 8];
        #pragma unroll
        for (int mi = 0; mi < 4; ++mi)
            #pragma unroll
            for (int ni = 0; ni < 4; ++ni)
                acc[mi][ni] = __builtin_amdgcn_mfma_f32_16x16x32_bf16(
                    af[mi], bfr[ni], acc[mi][ni], 0, 0, 0);
        __syncthreads();
    }

    // epilogue: C/D layout col = lane&15, row = quad*4 + reg
    #pragma unroll
    for (int mi = 0; mi < 4; ++mi) {
        int rowb = bm + wm + mi * 16 + quad * 4;
        #pragma unroll
        for (int ni = 0; ni < 4; ++ni) {
            int gn = bn + wn + ni * 16 + r;
            if (gn < N) {
                float bv = bias[gn];
                #pragma unroll
                for (int j = 0; j < 4; ++j) {
                    int orow = rowb + j;
                    if (revC) orow = M - 1 - orow;
                    float v = acc[mi][ni][j] + bv;
                    if (epi == 1) v = (v > 20.0f) ? v : log1pf(__expf(v));
                    C[(size_t)orow * ldc + gn] = v;
                }
            }
        }
    }
}

// ---- causal depthwise conv + silu ----
__global__ __launch_bounds__(256) void conv_k(
    const float* __restrict__ XZ, const float* __restrict__ cw,
    const float* __restrict__ cb, float* __restrict__ XC, float* __restrict__ SC)
{
    int idx = blockIdx.x * 256 + threadIdx.x;  // l*DI + d
    int d = idx & (DI - 1);
    int l = idx >> 10;
    float w0 = cw[d * 4 + 0], w1 = cw[d * 4 + 1], w2 = cw[d * 4 + 2], w3 = cw[d * 4 + 3];
    float acc = cb[d];
    if (l >= 3) acc += XZ[(size_t)(l - 3) * (2 * DI) + d] * w0;
    if (l >= 2) acc += XZ[(size_t)(l - 2) * (2 * DI) + d] * w1;
    if (l >= 1) acc += XZ[(size_t)(l - 1) * (2 * DI) + d] * w2;
    acc += XZ[(size_t)l * (2 * DI) + d] * w3;
    XC[idx] = acc;
    SC[idx] = acc * sigm(acc);
}

// ---- Phase A: per (dir, chunk, d): prod(dA), local h from h0=0 ----
__global__ __launch_bounds__(256) void scanA_k(
    const float* __restrict__ DT, const float* __restrict__ XC,
    const float* __restrict__ SP, const float* __restrict__ Alog,
    float* __restrict__ Pend, float* __restrict__ Hl)
{
    __shared__ float Bsh[CL][DS];
    int dir = blockIdx.z;
    int c = blockIdx.y;
    int d = blockIdx.x * 256 + threadIdx.x;
    DT += (size_t)dir * L_SEQ * DI;
    XC += (size_t)dir * L_SEQ * DI;
    SP += (size_t)dir * L_SEQ * NSP;
    int l0 = c * CL;
    for (int i = threadIdx.x; i < CL * DS; i += 256) {
        int ll = i >> 4, ss = i & 15;
        Bsh[ll][ss] = SP[(size_t)(l0 + ll) * NSP + DI + ss];
    }
    __syncthreads();
    float Ae[DS], h[DS], P[DS];
    #pragma unroll
    for (int s = 0; s < DS; ++s) { Ae[s] = -__expf(Alog[d * DS + s]); h[s] = 0.f; P[s] = 1.f; }
    for (int t = 0; t < CL; ++t) {
        int l = l0 + t;
        float dt = DT[(size_t)l * DI + d];
        float xv = XC[(size_t)l * DI + d];
        float dtx = dt * xv;
        #pragma unroll
        for (int s = 0; s < DS; ++s) {
            float e = __expf(dt * Ae[s]);
            h[s] = e * h[s] + dtx * Bsh[t][s];
            P[s] *= e;
        }
    }
    size_t o = ((size_t)(dir * NC + c) * DI + d) * DS;
    #pragma unroll
    for (int s = 0; s < DS; ++s) { Pend[o + s] = P[s]; Hl[o + s] = h[s]; }
}

// ---- Phase B: combine chunk summaries -> true chunk-start states ----
__global__ __launch_bounds__(256) void scanB_k(
    const float* __restrict__ Pend, const float* __restrict__ Hl, float* __restrict__ Hs)
{
    int idx = blockIdx.x * 256 + threadIdx.x;
    float h = 0.f;
    int ds = idx & 16383;
    int dir = idx >> 14;
    for (int c = 0; c < NC; ++c) {
        size_t o = ((size_t)(dir * NC + c)) * (DI * DS) + ds;
        Hs[o] = h;
        h = Pend[o] * h + Hl[o];
    }
}

// ---- Phase C: recompute within chunk; fuse y and silu(z) gate ----
__global__ __launch_bounds__(256) void scanC_k(
    const float* __restrict__ DT, const float* __restrict__ XC,
    const float* __restrict__ SP, const float* __restrict__ XZ,
    const float* __restrict__ Alog, const float* __restrict__ Dp,
    const float* __restrict__ Hs, float* __restrict__ G)
{
    __shared__ float Bsh[CL][DS];
    __shared__ float Csh[CL][DS];
    int dir = blockIdx.z;
    int c = blockIdx.y;
    int d = blockIdx.x * 256 + threadIdx.x;
    DT += (size_t)dir * L_SEQ * DI;
    XC += (size_t)dir * L_SEQ * DI;
    SP += (size_t)dir * L_SEQ * NSP;
    XZ += (size_t)dir * L_SEQ * (2 * DI);
    G  += (size_t)dir * L_SEQ * DI;
    int l0 = c * CL;
    for (int i = threadIdx.x; i < CL * DS; i += 256) {
        int ll = i >> 4, ss = i & 15;
        size_t base = (size_t)(l0 + ll) * NSP + DI;
        Bsh[ll][ss] = SP[base + ss];
        Csh[ll][ss] = SP[base + DS + ss];
    }
    __syncthreads();
    float Ae[DS], h[DS];
    size_t o = ((size_t)(dir * NC + c) * DI + d) * DS;
    #pragma unroll
    for (int s = 0; s < DS; ++s) { Ae[s] = -__expf(Alog[d * DS + s]); h[s] = Hs[o + s]; }
    float dpv = Dp[d];
    for (int t = 0; t < CL; ++t) {
        int l = l0 + t;
        float dt = DT[(size_t)l * DI + d];
        float xv = XC[(size_t)l * DI + d];
        float dtx = dt * xv;
        float y = 0.f;
        #pragma unroll
        for (int s = 0; s < DS; ++s) {
            float e = __expf(dt * Ae[s]);
            h[s] = e * h[s] + dtx * Bsh[t][s];
            y += h[s] * Csh[t][s];
        }
        y += dpv * xv;
        float z = XZ[(size_t)l * (2 * DI) + DI + d];
        G[(size_t)l * DI + d] = y * (z * sigm(z));
    }
}

extern "C" void kernel_launch(void* const* d_in, const int* in_sizes, int n_in,
                              void* d_out, int out_size, void* d_ws, size_t ws_size,
                              hipStream_t stream)
{
    (void)in_sizes; (void)n_in; (void)out_size; (void)ws_size;
    const float* x = (const float*)d_in[0];
    const float* inW[2]  = {(const float*)d_in[1],  (const float*)d_in[11]};
    const float* inb[2]  = {(const float*)d_in[2],  (const float*)d_in[12]};
    const float* cw[2]   = {(const float*)d_in[3],  (const float*)d_in[13]};
    const float* cb[2]   = {(const float*)d_in[4],  (const float*)d_in[14]};
    const float* xpW[2]  = {(const float*)d_in[5],  (const float*)d_in[15]};
    const float* xpb[2]  = {(const float*)d_in[6],  (const float*)d_in[16]};
    const float* dtW[2]  = {(const float*)d_in[7],  (const float*)d_in[17]};
    const float* dtb[2]  = {(const float*)d_in[8],  (const float*)d_in[18]};
    const float* outW[2] = {(const float*)d_in[9],  (const float*)d_in[19]};
    const float* outb[2] = {(const float*)d_in[10], (const float*)d_in[20]};
    const float* Alog = (const float*)d_in[21];
    const float* Dp   = (const float*)d_in[22];
    const float* fuW  = (const float*)d_in[23];
    const float* fub  = (const float*)d_in[24];
    float* out = (float*)d_out;

    float* ws = (float*)d_ws;
    size_t off = 0;
    auto alloc = [&](size_t n) { float* p = ws + off; off += n; return p; };
    float* XZ  = alloc((size_t)2 * L_SEQ * 2 * DI);
    float* XC  = alloc((size_t)2 * L_SEQ * DI);
    float* SC  = alloc((size_t)2 * L_SEQ * DI);
    float* SP  = alloc((size_t)2 * L_SEQ * NSP);
    float* DTb = alloc((size_t)2 * L_SEQ * DI);
    float* Pend= alloc((size_t)2 * NC * DI * DS);
    float* Hl  = alloc((size_t)2 * NC * DI * DS);
    float* Hs  = alloc((size_t)2 * NC * DI * DS);
    float* G   = alloc((size_t)2 * L_SEQ * DI);
    float* OC  = alloc((size_t)L_SEQ * DI);

    ushortT* wsu = (ushortT*)(ws + off);
    size_t uoff = 0;
    auto ualloc = [&](size_t n) { ushortT* p = wsu + uoff; uoff += n; return p; };
    ushortT* WtIn[2]  = {ualloc((size_t)2 * DI * DM), ualloc((size_t)2 * DI * DM)};      // [2048][512]
    ushortT* WtXp[2]  = {ualloc((size_t)NSP * DI),    ualloc((size_t)NSP * DI)};         // [1056][1024]
    ushortT* WtDt[2]  = {ualloc((size_t)DI * DI),     ualloc((size_t)DI * DI)};          // [1024][1024]
    ushortT* WtOut[2] = {ualloc((size_t)DM * DI),     ualloc((size_t)DM * DI)};          // [512][1024]
    ushortT* WtFu     = ualloc((size_t)DM * DI);                                         // [512][1024]

    dim3 blk(256);
    // 0) convert + transpose all weights to bf16 [N][K]
    for (int dir = 0; dir < 2; ++dir) {
        wcvt_k<<<dim3(2 * DI / 32, DM / 32), blk, 0, stream>>>(inW[dir],  WtIn[dir],  DM, 2 * DI);
        wcvt_k<<<dim3(NSP / 32,   DI / 32),  blk, 0, stream>>>(xpW[dir],  WtXp[dir],  DI, NSP);
        wcvt_k<<<dim3(DI / 32,    DI / 32),  blk, 0, stream>>>(dtW[dir],  WtDt[dir],  DI, DI);
        wcvt_k<<<dim3(DM / 32,    DI / 32),  blk, 0, stream>>>(outW[dir], WtOut[dir], DI, DM);
    }
    wcvt_k<<<dim3(DM / 32, DI / 32), blk, 0, stream>>>(fuW, WtFu, DI, DM);

    // 1) input projection (bwd reads x reversed)
    for (int dir = 0; dir < 2; ++dir)
        gemm_mfma<<<dim3(16, 16), blk, 0, stream>>>(
            x, DM, dir, WtIn[dir], inb[dir],
            XZ + (size_t)dir * L_SEQ * 2 * DI, 2 * DI, 0,
            L_SEQ, 2 * DI, DM, 0);
    // 2) causal depthwise conv + silu
    for (int dir = 0; dir < 2; ++dir)
        conv_k<<<dim3(L_SEQ * DI / 256), blk, 0, stream>>>(
            XZ + (size_t)dir * L_SEQ * 2 * DI, cw[dir], cb[dir],
            XC + (size_t)dir * L_SEQ * DI, SC + (size_t)dir * L_SEQ * DI);
    // 3) sp = silu(conv) @ xp_W + xp_b
    for (int dir = 0; dir < 2; ++dir)
        gemm_mfma<<<dim3(9, 16), blk, 0, stream>>>(
            SC + (size_t)dir * L_SEQ * DI, DI, 0, WtXp[dir], xpb[dir],
            SP + (size_t)dir * L_SEQ * NSP, NSP, 0,
            L_SEQ, NSP, DI, 0);
    // 4) dt = softplus(delta @ dt_W + dt_b)  (delta = first DI cols of SP)
    for (int dir = 0; dir < 2; ++dir)
        gemm_mfma<<<dim3(8, 16), blk, 0, stream>>>(
            SP + (size_t)dir * L_SEQ * NSP, NSP, 0, WtDt[dir], dtb[dir],
            DTb + (size_t)dir * L_SEQ * DI, DI, 0,
            L_SEQ, DI, DI, 1);
    // 5) chunked selective scan
    scanA_k<<<dim3(DI / 256, NC, 2), blk, 0, stream>>>(DTb, XC, SP, Alog, Pend, Hl);
    scanB_k<<<dim3(2 * DI * DS / 256), blk, 0, stream>>>(Pend, Hl, Hs);
    scanC_k<<<dim3(DI / 256, NC, 2), blk, 0, stream>>>(DTb, XC, SP, XZ, Alog, Dp, Hs, G);
    // 6) out projection into concat buffer (bwd rows reversed back)
    for (int dir = 0; dir < 2; ++dir)
        gemm_mfma<<<dim3(4, 16), blk, 0, stream>>>(
            G + (size_t)dir * L_SEQ * DI, DI, 0, WtOut[dir], outb[dir],
            OC + (size_t)dir * DM, DI, (dir == 1) ? 1 : 0,
            L_SEQ, DM, DI, 0);
    // 7) fusion GEMM -> final output
    gemm_mfma<<<dim3(4, 16), blk, 0, stream>>>(
        OC, DI, 0, WtFu, fub,
        out, DM, 0,
        L_SEQ, DM, DI, 0);
}

// Round 3
// 363.531 us; speedup vs baseline: 3.6644x; 1.7141x over previous
//
#include <hip/hip_runtime.h>
#include <cmath>

#define L_SEQ 2048
#define DM 512
#define DI 1024      // D_INNER
#define DS 16        // D_STATE
#define NSP 1056     // DI + 2*DS
#define NC 64        // scan chunks
#define CL 32        // chunk length (NC*CL == L_SEQ)

typedef unsigned short ushortT;
typedef unsigned int u32;
typedef __attribute__((ext_vector_type(8))) short short8;
typedef __attribute__((ext_vector_type(4))) float float4_t;
typedef __attribute__((address_space(1))) u32 gu32;
typedef __attribute__((address_space(3))) u32 lu32;

__device__ __forceinline__ float sigm(float x) { return 1.0f / (1.0f + __expf(-x)); }

__device__ __forceinline__ ushortT f2bf(float f) {
    unsigned u = __float_as_uint(f);
    unsigned r = u + 0x7FFFu + ((u >> 16) & 1u);
    return (ushortT)(r >> 16);
}

__device__ __forceinline__ void gl2lds16(const ushortT* g, ushortT* l) {
    __builtin_amdgcn_global_load_lds((gu32*)g, (lu32*)l, 16, 0, 0);
}

// ---- weight convert + transpose: W[K][N] fp32 -> Wt[N][K] bf16 ----
__global__ __launch_bounds__(256) void wcvt_k(const float* __restrict__ W,
                                              ushortT* __restrict__ Wt,
                                              int K, int N)
{
    __shared__ ushortT t[32][33];
    int n0 = blockIdx.x * 32, k0 = blockIdx.y * 32;
    int tx = threadIdx.x & 31, ty = threadIdx.x >> 5;   // 32 x 8
    #pragma unroll
    for (int i = 0; i < 32; i += 8)
        t[ty + i][tx] = f2bf(W[(size_t)(k0 + ty + i) * N + n0 + tx]);
    __syncthreads();
    #pragma unroll
    for (int i = 0; i < 32; i += 8)
        Wt[(size_t)(n0 + ty + i) * K + k0 + tx] = t[tx][ty + i];
}

// ---- x fp32 -> bf16 ----
__global__ __launch_bounds__(256) void xcvt_k(const float* __restrict__ x,
                                              ushortT* __restrict__ xb, int n)
{
    int i = (blockIdx.x * 256 + threadIdx.x) * 4;
    if (i < n) {
        float4_t v = *(const float4_t*)(x + i);
        xb[i + 0] = f2bf(v[0]); xb[i + 1] = f2bf(v[1]);
        xb[i + 2] = f2bf(v[2]); xb[i + 3] = f2bf(v[3]);
    }
}

// ---- bf16 MFMA GEMM, both dirs in one dispatch (blockIdx.z = dir) ----
// A[M][lda] bf16 (+dir*Astr), Wt[N][K] bf16 (+dir*Wstr).
// Cf fp32 out (may be null), Cb bf16 out (may be null, cols < Nbmax).
// revAmode/revCmode: 0 = never, 2 = reverse rows when dir==1.
// epi: 0 none, 1 softplus.
template<int BM, int BN>
__global__ __launch_bounds__(256, 2) void gemm_bf16(
    const ushortT* __restrict__ A, int lda, long long Astr, int revAmode,
    const ushortT* __restrict__ W, long long Wstr,
    const float* __restrict__ bias0, const float* __restrict__ bias1,
    float* __restrict__ Cf, int ldcf, long long Cfstr,
    ushortT* __restrict__ Cb, int ldcb, long long Cbstr, int Nbmax,
    int revCmode, int M, int N, int K, int epi)
{
    const int dir = blockIdx.z;
    A  += (size_t)dir * Astr;
    W  += (size_t)dir * Wstr;
    if (Cf) Cf += (size_t)dir * Cfstr;
    if (Cb) Cb += (size_t)dir * Cbstr;
    const float* bias = dir ? bias1 : bias0;
    const int revA = (revAmode == 2) ? dir : revAmode;
    const int revC = (revCmode == 2) ? dir : revCmode;

    constexpr int MI = BM / 32;      // 16-row MFMA tiles per wave (M)
    constexpr int NI = BN / 32;      // per wave (N)
    constexpr int CA = BM / 64;      // staging calls for A
    constexpr int CB = BN / 64;

    __shared__ ushortT As[BM * 32];
    __shared__ ushortT Bs[BN * 32];

    const int tid  = threadIdx.x;
    const int wave = tid >> 6;
    const int lane = tid & 63;
    const int quad = lane >> 4;
    const int r    = lane & 15;
    const int wm   = (wave >> 1) * (BM / 2);
    const int wn   = (wave & 1) * (BN / 2);
    const int bm   = blockIdx.y * BM;
    const int bn   = blockIdx.x * BN;

    const int lrow = lane >> 2;          // 0..15
    const int lk   = (lane & 3) * 8;     // shorts

    // per-lane global pointers, wave-uniform LDS bases
    const ushortT* gA[CA];
    ushortT* lA[CA];
    #pragma unroll
    for (int c = 0; c < CA; ++c) {
        int row = bm + c * 64 + wave * 16 + lrow;
        if (revA) row = M - 1 - row;
        gA[c] = A + (size_t)row * lda + lk;
        lA[c] = As + (c * 64 + wave * 16) * 32;
    }
    const ushortT* gB[CB];
    ushortT* lB[CB];
    #pragma unroll
    for (int c = 0; c < CB; ++c) {
        int row = bn + c * 64 + wave * 16 + lrow;
        if (row > N - 1) row = N - 1;
        gB[c] = W + (size_t)row * K + lk;
        lB[c] = Bs + (c * 64 + wave * 16) * 32;
    }

    float4_t acc[MI][NI];
    #pragma unroll
    for (int i = 0; i < MI; ++i)
        #pragma unroll
        for (int j = 0; j < NI; ++j)
            acc[i][j] = (float4_t){0.f, 0.f, 0.f, 0.f};

    for (int k0 = 0; k0 < K; k0 += 32) {
        #pragma unroll
        for (int c = 0; c < CA; ++c) gl2lds16(gA[c] + k0, lA[c]);
        #pragma unroll
        for (int c = 0; c < CB; ++c) gl2lds16(gB[c] + k0, lB[c]);
        __syncthreads();

        short8 af[MI], bf[NI];
        #pragma unroll
        for (int mi = 0; mi < MI; ++mi)
            af[mi] = *(const short8*)&As[(wm + mi * 16 + r) * 32 + quad * 8];
        #pragma unroll
        for (int ni = 0; ni < NI; ++ni)
            bf[ni] = *(const short8*)&Bs[(wn + ni * 16 + r) * 32 + quad * 8];
        #pragma unroll
        for (int mi = 0; mi < MI; ++mi)
            #pragma unroll
            for (int ni = 0; ni < NI; ++ni)
                acc[mi][ni] = __builtin_amdgcn_mfma_f32_16x16x32_bf16(
                    af[mi], bf[ni], acc[mi][ni], 0, 0, 0);
        __syncthreads();
    }

    // epilogue: C/D layout col = lane&15, row = quad*4 + reg
    #pragma unroll
    for (int mi = 0; mi < MI; ++mi) {
        int rowb = bm + wm + mi * 16 + quad * 4;
        #pragma unroll
        for (int ni = 0; ni < NI; ++ni) {
            int gn = bn + wn + ni * 16 + r;
            if (gn < N) {
                float bv = bias[gn];
                #pragma unroll
                for (int j = 0; j < 4; ++j) {
                    int orow = rowb + j;
                    if (revC) orow = M - 1 - orow;
                    float v = acc[mi][ni][j] + bv;
                    if (epi == 1) v = (v > 20.0f) ? v : log1pf(__expf(v));
                    if (Cf) Cf[(size_t)orow * ldcf + gn] = v;
                    if (Cb && gn < Nbmax) Cb[(size_t)orow * ldcb + gn] = f2bf(v);
                }
            }
        }
    }
}

// ---- causal depthwise conv: XC fp32 + silu(conv) bf16 ----
__global__ __launch_bounds__(256) void conv_k(
    const float* __restrict__ XZ, const float* __restrict__ cw,
    const float* __restrict__ cb, float* __restrict__ XC, ushortT* __restrict__ SCb)
{
    int idx = blockIdx.x * 256 + threadIdx.x;  // l*DI + d
    int d = idx & (DI - 1);
    int l = idx >> 10;
    float w0 = cw[d * 4 + 0], w1 = cw[d * 4 + 1], w2 = cw[d * 4 + 2], w3 = cw[d * 4 + 3];
    float acc = cb[d];
    if (l >= 3) acc += XZ[(size_t)(l - 3) * (2 * DI) + d] * w0;
    if (l >= 2) acc += XZ[(size_t)(l - 2) * (2 * DI) + d] * w1;
    if (l >= 1) acc += XZ[(size_t)(l - 1) * (2 * DI) + d] * w2;
    acc += XZ[(size_t)l * (2 * DI) + d] * w3;
    XC[idx] = acc;
    SCb[idx] = f2bf(acc * sigm(acc));
}

// ---- Phase A: per (dir, chunk, d): prod(dA), local h from h0=0 ----
__global__ __launch_bounds__(256) void scanA_k(
    const float* __restrict__ DT, const float* __restrict__ XC,
    const float* __restrict__ SP, const float* __restrict__ Alog,
    float* __restrict__ Pend, float* __restrict__ Hl)
{
    __shared__ float Bsh[CL][DS];
    int dir = blockIdx.z;
    int c = blockIdx.y;
    int d = blockIdx.x * 256 + threadIdx.x;
    DT += (size_t)dir * L_SEQ * DI;
    XC += (size_t)dir * L_SEQ * DI;
    SP += (size_t)dir * L_SEQ * NSP;
    int l0 = c * CL;
    for (int i = threadIdx.x; i < CL * DS; i += 256) {
        int ll = i >> 4, ss = i & 15;
        Bsh[ll][ss] = SP[(size_t)(l0 + ll) * NSP + DI + ss];
    }
    __syncthreads();
    float Ae[DS], h[DS], P[DS];
    #pragma unroll
    for (int s = 0; s < DS; ++s) { Ae[s] = -__expf(Alog[d * DS + s]); h[s] = 0.f; P[s] = 1.f; }
    for (int t = 0; t < CL; ++t) {
        int l = l0 + t;
        float dt = DT[(size_t)l * DI + d];
        float xv = XC[(size_t)l * DI + d];
        float dtx = dt * xv;
        #pragma unroll
        for (int s = 0; s < DS; ++s) {
            float e = __expf(dt * Ae[s]);
            h[s] = e * h[s] + dtx * Bsh[t][s];
            P[s] *= e;
        }
    }
    size_t o = ((size_t)(dir * NC + c) * DI + d) * DS;
    #pragma unroll
    for (int s = 0; s < DS; ++s) { Pend[o + s] = P[s]; Hl[o + s] = h[s]; }
}

// ---- Phase B: combine chunk summaries -> true chunk-start states ----
__global__ __launch_bounds__(256) void scanB_k(
    const float* __restrict__ Pend, const float* __restrict__ Hl, float* __restrict__ Hs)
{
    int idx = blockIdx.x * 256 + threadIdx.x;
    float h = 0.f;
    int ds = idx & 16383;
    int dir = idx >> 14;
    for (int c = 0; c < NC; ++c) {
        size_t o = ((size_t)(dir * NC + c)) * (DI * DS) + ds;
        Hs[o] = h;
        h = Pend[o] * h + Hl[o];
    }
}

// ---- Phase C: recompute within chunk; fuse y, D-skip, silu(z) gate -> bf16 ----
__global__ __launch_bounds__(256) void scanC_k(
    const float* __restrict__ DT, const float* __restrict__ XC,
    const float* __restrict__ SP, const float* __restrict__ XZ,
    const float* __restrict__ Alog, const float* __restrict__ Dp,
    const float* __restrict__ Hs, ushortT* __restrict__ Gb)
{
    __shared__ float Bsh[CL][DS];
    __shared__ float Csh[CL][DS];
    int dir = blockIdx.z;
    int c = blockIdx.y;
    int d = blockIdx.x * 256 + threadIdx.x;
    DT += (size_t)dir * L_SEQ * DI;
    XC += (size_t)dir * L_SEQ * DI;
    SP += (size_t)dir * L_SEQ * NSP;
    XZ += (size_t)dir * L_SEQ * (2 * DI);
    Gb += (size_t)dir * L_SEQ * DI;
    int l0 = c * CL;
    for (int i = threadIdx.x; i < CL * DS; i += 256) {
        int ll = i >> 4, ss = i & 15;
        size_t base = (size_t)(l0 + ll) * NSP + DI;
        Bsh[ll][ss] = SP[base + ss];
        Csh[ll][ss] = SP[base + DS + ss];
    }
    __syncthreads();
    float Ae[DS], h[DS];
    size_t o = ((size_t)(dir * NC + c) * DI + d) * DS;
    #pragma unroll
    for (int s = 0; s < DS; ++s) { Ae[s] = -__expf(Alog[d * DS + s]); h[s] = Hs[o + s]; }
    float dpv = Dp[d];
    for (int t = 0; t < CL; ++t) {
        int l = l0 + t;
        float dt = DT[(size_t)l * DI + d];
        float xv = XC[(size_t)l * DI + d];
        float dtx = dt * xv;
        float y = 0.f;
        #pragma unroll
        for (int s = 0; s < DS; ++s) {
            float e = __expf(dt * Ae[s]);
            h[s] = e * h[s] + dtx * Bsh[t][s];
            y += h[s] * Csh[t][s];
        }
        y += dpv * xv;
        float z = XZ[(size_t)l * (2 * DI) + DI + d];
        Gb[(size_t)l * DI + d] = f2bf(y * (z * sigm(z)));
    }
}

extern "C" void kernel_launch(void* const* d_in, const int* in_sizes, int n_in,
                              void* d_out, int out_size, void* d_ws, size_t ws_size,
                              hipStream_t stream)
{
    (void)in_sizes; (void)n_in; (void)out_size; (void)ws_size;
    const float* x = (const float*)d_in[0];
    const float* inW[2]  = {(const float*)d_in[1],  (const float*)d_in[11]};
    const float* inb[2]  = {(const float*)d_in[2],  (const float*)d_in[12]};
    const float* cw[2]   = {(const float*)d_in[3],  (const float*)d_in[13]};
    const float* cb[2]   = {(const float*)d_in[4],  (const float*)d_in[14]};
    const float* xpW[2]  = {(const float*)d_in[5],  (const float*)d_in[15]};
    const float* xpb[2]  = {(const float*)d_in[6],  (const float*)d_in[16]};
    const float* dtW[2]  = {(const float*)d_in[7],  (const float*)d_in[17]};
    const float* dtb[2]  = {(const float*)d_in[8],  (const float*)d_in[18]};
    const float* outW[2] = {(const float*)d_in[9],  (const float*)d_in[19]};
    const float* outb[2] = {(const float*)d_in[10], (const float*)d_in[20]};
    const float* Alog = (const float*)d_in[21];
    const float* Dp   = (const float*)d_in[22];
    const float* fuW  = (const float*)d_in[23];
    const float* fub  = (const float*)d_in[24];
    float* out = (float*)d_out;

    float* ws = (float*)d_ws;
    size_t off = 0;
    auto alloc = [&](size_t n) { float* p = ws + off; off += n; return p; };
    float* XZ  = alloc((size_t)2 * L_SEQ * 2 * DI);   // in-proj out (x_ssm | z), fp32
    float* XC  = alloc((size_t)2 * L_SEQ * DI);       // conv out fp32
    float* SP  = alloc((size_t)2 * L_SEQ * NSP);      // delta | B | C fp32
    float* DTb = alloc((size_t)2 * L_SEQ * DI);       // softplus dt fp32
    float* Pend= alloc((size_t)2 * NC * DI * DS);
    float* Hl  = alloc((size_t)2 * NC * DI * DS);
    float* Hs  = alloc((size_t)2 * NC * DI * DS);

    ushortT* wsu = (ushortT*)(ws + off);
    size_t uoff = 0;
    auto ualloc = [&](size_t n) { ushortT* p = wsu + uoff; uoff += n; return p; };
    // weights: per-dir pairs allocated contiguously so Wstr = per-dir size
    ushortT* WtIn  = ualloc((size_t)2 * (2 * DI) * DM);   // [dir][2048][512]
    ushortT* WtXp  = ualloc((size_t)2 * NSP * DI);        // [dir][1056][1024]
    ushortT* WtDt  = ualloc((size_t)2 * DI * DI);         // [dir][1024][1024]
    ushortT* WtOut = ualloc((size_t)2 * DM * DI);         // [dir][512][1024]
    ushortT* WtFu  = ualloc((size_t)DM * DI);             // [512][1024]
    ushortT* XB    = ualloc((size_t)L_SEQ * DM);          // bf16 x
    ushortT* SCb   = ualloc((size_t)2 * L_SEQ * DI);      // bf16 silu(conv)
    ushortT* SPb   = ualloc((size_t)2 * L_SEQ * DI);      // bf16 delta
    ushortT* Gb    = ualloc((size_t)2 * L_SEQ * DI);      // bf16 gated y
    ushortT* OCb   = ualloc((size_t)L_SEQ * DI);          // bf16 concat(out_fwd,out_bwd)

    dim3 blk(256);
    // 0) weight conversions + x conversion
    for (int dir = 0; dir < 2; ++dir) {
        wcvt_k<<<dim3(2 * DI / 32, DM / 32), blk, 0, stream>>>(inW[dir],  WtIn  + (size_t)dir * 2 * DI * DM, DM, 2 * DI);
        wcvt_k<<<dim3(NSP / 32,   DI / 32),  blk, 0, stream>>>(xpW[dir],  WtXp  + (size_t)dir * NSP * DI,    DI, NSP);
        wcvt_k<<<dim3(DI / 32,    DI / 32),  blk, 0, stream>>>(dtW[dir],  WtDt  + (size_t)dir * DI * DI,     DI, DI);
        wcvt_k<<<dim3(DM / 32,    DI / 32),  blk, 0, stream>>>(outW[dir], WtOut + (size_t)dir * DM * DI,     DI, DM);
    }
    wcvt_k<<<dim3(DM / 32, DI / 32), blk, 0, stream>>>(fuW, WtFu, DI, DM);
    xcvt_k<<<dim3(L_SEQ * DM / 1024), blk, 0, stream>>>(x, XB, L_SEQ * DM);

    // 1) input projection, both dirs (dir1 reads x reversed)
    gemm_bf16<128, 128><<<dim3(16, 16, 2), blk, 0, stream>>>(
        XB, DM, 0, 2, WtIn, (long long)2 * DI * DM, inb[0], inb[1],
        XZ, 2 * DI, (long long)L_SEQ * 2 * DI, nullptr, 0, 0, 0,
        0, L_SEQ, 2 * DI, DM, 0);
    // 2) causal depthwise conv + silu (both dirs, separate trivial dispatches)
    for (int dir = 0; dir < 2; ++dir)
        conv_k<<<dim3(L_SEQ * DI / 256), blk, 0, stream>>>(
            XZ + (size_t)dir * L_SEQ * 2 * DI, cw[dir], cb[dir],
            XC + (size_t)dir * L_SEQ * DI, SCb + (size_t)dir * L_SEQ * DI);
    // 3) sp = silu(conv) @ xp_W + xp_b  (fp32 SP + bf16 delta shadow)
    gemm_bf16<128, 64><<<dim3((NSP + 63) / 64, 16, 2), blk, 0, stream>>>(
        SCb, DI, (long long)L_SEQ * DI, 0, WtXp, (long long)NSP * DI, xpb[0], xpb[1],
        SP, NSP, (long long)L_SEQ * NSP, SPb, DI, (long long)L_SEQ * DI, DI,
        0, L_SEQ, NSP, DI, 0);
    // 4) dt = softplus(delta @ dt_W + dt_b)
    gemm_bf16<128, 64><<<dim3(16, 16, 2), blk, 0, stream>>>(
        SPb, DI, (long long)L_SEQ * DI, 0, WtDt, (long long)DI * DI, dtb[0], dtb[1],
        DTb, DI, (long long)L_SEQ * DI, nullptr, 0, 0, 0,
        0, L_SEQ, DI, DI, 1);
    // 5) chunked selective scan
    scanA_k<<<dim3(DI / 256, NC, 2), blk, 0, stream>>>(DTb, XC, SP, Alog, Pend, Hl);
    scanB_k<<<dim3(2 * DI * DS / 256), blk, 0, stream>>>(Pend, Hl, Hs);
    scanC_k<<<dim3(DI / 256, NC, 2), blk, 0, stream>>>(DTb, XC, SP, XZ, Alog, Dp, Hs, Gb);
    // 6) out projection -> bf16 concat buffer (dir1 rows reversed back, cols offset DM)
    gemm_bf16<64, 64><<<dim3(8, 32, 2), blk, 0, stream>>>(
        Gb, DI, (long long)L_SEQ * DI, 0, WtOut, (long long)DM * DI, outb[0], outb[1],
        nullptr, 0, 0, OCb, DI, (long long)DM, DM,
        2, L_SEQ, DM, DI, 0);
    // 7) fusion GEMM -> final output
    gemm_bf16<64, 64><<<dim3(8, 32, 1), blk, 0, stream>>>(
        OCb, DI, 0, 0, WtFu, 0, fub, fub,
        out, DM, (long long)0, nullptr, 0, 0, 0,
        0, L_SEQ, DM, DI, 0);
}

// Round 4
// 346.772 us; speedup vs baseline: 3.8415x; 1.0483x over previous
//
#include <hip/hip_runtime.h>
#include <cmath>

#define L_SEQ 2048
#define DM 512
#define DI 1024      // D_INNER
#define DS 16        // D_STATE
#define NSP 1056     // DI + 2*DS
#define NC 64        // scan chunks
#define CL 32        // chunk length (NC*CL == L_SEQ)

typedef unsigned short ushortT;
typedef unsigned int u32;
typedef __attribute__((ext_vector_type(8))) short short8;
typedef __attribute__((ext_vector_type(4))) float float4_t;
typedef __attribute__((address_space(1))) u32 gu32;
typedef __attribute__((address_space(3))) u32 lu32;

__device__ __forceinline__ float sigm(float x) { return 1.0f / (1.0f + __expf(-x)); }

__device__ __forceinline__ ushortT f2bf(float f) {
    unsigned u = __float_as_uint(f);
    unsigned r = u + 0x7FFFu + ((u >> 16) & 1u);
    return (ushortT)(r >> 16);
}

__device__ __forceinline__ void gl2lds16(const ushortT* g, ushortT* l) {
    __builtin_amdgcn_global_load_lds((gu32*)g, (lu32*)l, 16, 0, 0);
}

// ---- batched weight convert + transpose: 9 matrices, one dispatch ----
// W[K][N] fp32 -> Wt[N][K] bf16
struct WC {
    const float* src[9];
    ushortT* dst[9];
    int K[9], N[9], tN[9];
    int off[10];
};

__global__ __launch_bounds__(256) void wcvt_all(WC wc)
{
    __shared__ ushortT t[32][33];
    int b = blockIdx.x;
    int m = 0;
    while (b >= wc.off[m + 1]) ++m;
    int tl = b - wc.off[m];
    int n0 = (tl % wc.tN[m]) * 32;
    int k0 = (tl / wc.tN[m]) * 32;
    const float* W = wc.src[m];
    ushortT* Wt = wc.dst[m];
    int K = wc.K[m], N = wc.N[m];
    int tx = threadIdx.x & 31, ty = threadIdx.x >> 5;   // 32 x 8
    #pragma unroll
    for (int i = 0; i < 32; i += 8)
        t[ty + i][tx] = f2bf(W[(size_t)(k0 + ty + i) * N + n0 + tx]);
    __syncthreads();
    #pragma unroll
    for (int i = 0; i < 32; i += 8)
        Wt[(size_t)(n0 + ty + i) * K + k0 + tx] = t[tx][ty + i];
}

// ---- x fp32 -> bf16 ----
__global__ __launch_bounds__(256) void xcvt_k(const float* __restrict__ x,
                                              ushortT* __restrict__ xb, int n)
{
    int i = (blockIdx.x * 256 + threadIdx.x) * 4;
    if (i < n) {
        float4_t v = *(const float4_t*)(x + i);
        xb[i + 0] = f2bf(v[0]); xb[i + 1] = f2bf(v[1]);
        xb[i + 2] = f2bf(v[2]); xb[i + 3] = f2bf(v[3]);
    }
}

// ---- bf16 MFMA GEMM, double-buffered (1 barrier/step), dirs in blockIdx.z ----
template<int BM, int BN>
__global__ __launch_bounds__(256, 2) void gemm_bf16(
    const ushortT* __restrict__ A, int lda, long long Astr, int revAmode,
    const ushortT* __restrict__ W, long long Wstr,
    const float* __restrict__ bias0, const float* __restrict__ bias1,
    float* __restrict__ Cf, int ldcf, long long Cfstr,
    ushortT* __restrict__ Cb, int ldcb, long long Cbstr, int Nbmax,
    int revCmode, int M, int N, int K, int epi)
{
    const int dir = blockIdx.z;
    A  += (size_t)dir * Astr;
    W  += (size_t)dir * Wstr;
    if (Cf) Cf += (size_t)dir * Cfstr;
    if (Cb) Cb += (size_t)dir * Cbstr;
    const float* bias = dir ? bias1 : bias0;
    const int revA = (revAmode == 2) ? dir : revAmode;
    const int revC = (revCmode == 2) ? dir : revCmode;

    constexpr int MI = BM / 32;
    constexpr int NI = BN / 32;
    constexpr int CA = BM / 64;
    constexpr int CB = BN / 64;

    __shared__ ushortT As[2][BM * 32];
    __shared__ ushortT Bs[2][BN * 32];

    const int tid  = threadIdx.x;
    const int wave = tid >> 6;
    const int lane = tid & 63;
    const int quad = lane >> 4;
    const int r    = lane & 15;
    const int wm   = (wave >> 1) * (BM / 2);
    const int wn   = (wave & 1) * (BN / 2);
    const int bm   = blockIdx.y * BM;
    const int bn   = blockIdx.x * BN;

    const int lrow = lane >> 2;          // 0..15
    const int lk   = (lane & 3) * 8;     // shorts

    const ushortT* gA[CA];
    ushortT* lA[CA];
    #pragma unroll
    for (int c = 0; c < CA; ++c) {
        int row = bm + c * 64 + wave * 16 + lrow;
        if (revA) row = M - 1 - row;
        gA[c] = A + (size_t)row * lda + lk;
        lA[c] = &As[0][(c * 64 + wave * 16) * 32];
    }
    const ushortT* gB[CB];
    ushortT* lB[CB];
    #pragma unroll
    for (int c = 0; c < CB; ++c) {
        int row = bn + c * 64 + wave * 16 + lrow;
        if (row > N - 1) row = N - 1;
        gB[c] = W + (size_t)row * K + lk;
        lB[c] = &Bs[0][(c * 64 + wave * 16) * 32];
    }
    constexpr int ABUF = BM * 32;
    constexpr int BBUF = BN * 32;

    float4_t acc[MI][NI];
    #pragma unroll
    for (int i = 0; i < MI; ++i)
        #pragma unroll
        for (int j = 0; j < NI; ++j)
            acc[i][j] = (float4_t){0.f, 0.f, 0.f, 0.f};

    const int nsteps = K >> 5;   // K/32, always even here

    // prologue: stage step 0 into buffer 0
    #pragma unroll
    for (int c = 0; c < CA; ++c) gl2lds16(gA[c], lA[c]);
    #pragma unroll
    for (int c = 0; c < CB; ++c) gl2lds16(gB[c], lB[c]);

    for (int i = 0; i < nsteps; i += 2) {
        // ---- step i (compute buf0, prefetch i+1 -> buf1) ----
        __syncthreads();
        {
            int kq = (i + 1) << 5;
            if (i + 1 < nsteps) {
                #pragma unroll
                for (int c = 0; c < CA; ++c) gl2lds16(gA[c] + kq, lA[c] + ABUF);
                #pragma unroll
                for (int c = 0; c < CB; ++c) gl2lds16(gB[c] + kq, lB[c] + BBUF);
            }
        }
        {
            short8 af[MI], bf[NI];
            #pragma unroll
            for (int mi = 0; mi < MI; ++mi)
                af[mi] = *(const short8*)&As[0][(wm + mi * 16 + r) * 32 + quad * 8];
            #pragma unroll
            for (int ni = 0; ni < NI; ++ni)
                bf[ni] = *(const short8*)&Bs[0][(wn + ni * 16 + r) * 32 + quad * 8];
            #pragma unroll
            for (int mi = 0; mi < MI; ++mi)
                #pragma unroll
                for (int ni = 0; ni < NI; ++ni)
                    acc[mi][ni] = __builtin_amdgcn_mfma_f32_16x16x32_bf16(
                        af[mi], bf[ni], acc[mi][ni], 0, 0, 0);
        }
        // ---- step i+1 (compute buf1, prefetch i+2 -> buf0) ----
        __syncthreads();
        {
            int kq = (i + 2) << 5;
            if (i + 2 < nsteps) {
                #pragma unroll
                for (int c = 0; c < CA; ++c) gl2lds16(gA[c] + kq, lA[c]);
                #pragma unroll
                for (int c = 0; c < CB; ++c) gl2lds16(gB[c] + kq, lB[c]);
            }
        }
        {
            short8 af[MI], bf[NI];
            #pragma unroll
            for (int mi = 0; mi < MI; ++mi)
                af[mi] = *(const short8*)&As[1][(wm + mi * 16 + r) * 32 + quad * 8];
            #pragma unroll
            for (int ni = 0; ni < NI; ++ni)
                bf[ni] = *(const short8*)&Bs[1][(wn + ni * 16 + r) * 32 + quad * 8];
            #pragma unroll
            for (int mi = 0; mi < MI; ++mi)
                #pragma unroll
                for (int ni = 0; ni < NI; ++ni)
                    acc[mi][ni] = __builtin_amdgcn_mfma_f32_16x16x32_bf16(
                        af[mi], bf[ni], acc[mi][ni], 0, 0, 0);
        }
    }

    // epilogue: C/D layout col = lane&15, row = quad*4 + reg
    #pragma unroll
    for (int mi = 0; mi < MI; ++mi) {
        int rowb = bm + wm + mi * 16 + quad * 4;
        #pragma unroll
        for (int ni = 0; ni < NI; ++ni) {
            int gn = bn + wn + ni * 16 + r;
            if (gn < N) {
                float bv = bias[gn];
                #pragma unroll
                for (int j = 0; j < 4; ++j) {
                    int orow = rowb + j;
                    if (revC) orow = M - 1 - orow;
                    float v = acc[mi][ni][j] + bv;
                    if (epi == 1) v = (v > 20.0f) ? v : log1pf(__expf(v));
                    if (Cf) Cf[(size_t)orow * ldcf + gn] = v;
                    if (Cb && gn < Nbmax) Cb[(size_t)orow * ldcb + gn] = f2bf(v);
                }
            }
        }
    }
}

// ---- causal depthwise conv: XC fp32 + silu(conv) bf16, both dirs ----
__global__ __launch_bounds__(256) void conv_k(
    const float* __restrict__ XZ,
    const float* __restrict__ cw0, const float* __restrict__ cw1,
    const float* __restrict__ cb0, const float* __restrict__ cb1,
    float* __restrict__ XC, ushortT* __restrict__ SCb)
{
    int dir = blockIdx.z;
    XZ += (size_t)dir * L_SEQ * 2 * DI;
    XC += (size_t)dir * L_SEQ * DI;
    SCb += (size_t)dir * L_SEQ * DI;
    const float* cw = dir ? cw1 : cw0;
    const float* cb = dir ? cb1 : cb0;
    int idx = blockIdx.x * 256 + threadIdx.x;  // l*DI + d
    int d = idx & (DI - 1);
    int l = idx >> 10;
    float w0 = cw[d * 4 + 0], w1 = cw[d * 4 + 1], w2 = cw[d * 4 + 2], w3 = cw[d * 4 + 3];
    float acc = cb[d];
    if (l >= 3) acc += XZ[(size_t)(l - 3) * (2 * DI) + d] * w0;
    if (l >= 2) acc += XZ[(size_t)(l - 2) * (2 * DI) + d] * w1;
    if (l >= 1) acc += XZ[(size_t)(l - 1) * (2 * DI) + d] * w2;
    acc += XZ[(size_t)l * (2 * DI) + d] * w3;
    XC[idx] = acc;
    SCb[idx] = f2bf(acc * sigm(acc));
}

// ---- Phase A: per (dir, chunk, d): prod(dA), local h from h0=0 ----
__global__ __launch_bounds__(256) void scanA_k(
    const float* __restrict__ DT, const float* __restrict__ XC,
    const float* __restrict__ SP, const float* __restrict__ Alog,
    float* __restrict__ Pend, float* __restrict__ Hl)
{
    __shared__ float Bsh[CL][DS];
    int dir = blockIdx.z;
    int c = blockIdx.y;
    int d = blockIdx.x * 256 + threadIdx.x;
    DT += (size_t)dir * L_SEQ * DI;
    XC += (size_t)dir * L_SEQ * DI;
    SP += (size_t)dir * L_SEQ * NSP;
    int l0 = c * CL;
    for (int i = threadIdx.x; i < CL * DS; i += 256) {
        int ll = i >> 4, ss = i & 15;
        Bsh[ll][ss] = SP[(size_t)(l0 + ll) * NSP + DI + ss];
    }
    __syncthreads();
    float Ae[DS], h[DS], P[DS];
    #pragma unroll
    for (int s = 0; s < DS; ++s) { Ae[s] = -__expf(Alog[d * DS + s]); h[s] = 0.f; P[s] = 1.f; }
    for (int t = 0; t < CL; ++t) {
        int l = l0 + t;
        float dt = DT[(size_t)l * DI + d];
        float xv = XC[(size_t)l * DI + d];
        float dtx = dt * xv;
        #pragma unroll
        for (int s = 0; s < DS; ++s) {
            float e = __expf(dt * Ae[s]);
            h[s] = e * h[s] + dtx * Bsh[t][s];
            P[s] *= e;
        }
    }
    size_t o = ((size_t)(dir * NC + c) * DI + d) * DS;
    #pragma unroll
    for (int s = 0; s < DS; ++s) { Pend[o + s] = P[s]; Hl[o + s] = h[s]; }
}

// ---- Phase B: combine chunk summaries -> true chunk-start states ----
__global__ __launch_bounds__(256) void scanB_k(
    const float* __restrict__ Pend, const float* __restrict__ Hl, float* __restrict__ Hs)
{
    int idx = blockIdx.x * 256 + threadIdx.x;
    float h = 0.f;
    int ds = idx & 16383;
    int dir = idx >> 14;
    for (int c = 0; c < NC; ++c) {
        size_t o = ((size_t)(dir * NC + c)) * (DI * DS) + ds;
        Hs[o] = h;
        h = Pend[o] * h + Hl[o];
    }
}

// ---- Phase C: recompute within chunk; fuse y, D-skip, silu(z) gate -> bf16 ----
__global__ __launch_bounds__(256) void scanC_k(
    const float* __restrict__ DT, const float* __restrict__ XC,
    const float* __restrict__ SP, const float* __restrict__ XZ,
    const float* __restrict__ Alog, const float* __restrict__ Dp,
    const float* __restrict__ Hs, ushortT* __restrict__ Gb)
{
    __shared__ float Bsh[CL][DS];
    __shared__ float Csh[CL][DS];
    int dir = blockIdx.z;
    int c = blockIdx.y;
    int d = blockIdx.x * 256 + threadIdx.x;
    DT += (size_t)dir * L_SEQ * DI;
    XC += (size_t)dir * L_SEQ * DI;
    SP += (size_t)dir * L_SEQ * NSP;
    XZ += (size_t)dir * L_SEQ * (2 * DI);
    Gb += (size_t)dir * L_SEQ * DI;
    int l0 = c * CL;
    for (int i = threadIdx.x; i < CL * DS; i += 256) {
        int ll = i >> 4, ss = i & 15;
        size_t base = (size_t)(l0 + ll) * NSP + DI;
        Bsh[ll][ss] = SP[base + ss];
        Csh[ll][ss] = SP[base + DS + ss];
    }
    __syncthreads();
    float Ae[DS], h[DS];
    size_t o = ((size_t)(dir * NC + c) * DI + d) * DS;
    #pragma unroll
    for (int s = 0; s < DS; ++s) { Ae[s] = -__expf(Alog[d * DS + s]); h[s] = Hs[o + s]; }
    float dpv = Dp[d];
    for (int t = 0; t < CL; ++t) {
        int l = l0 + t;
        float dt = DT[(size_t)l * DI + d];
        float xv = XC[(size_t)l * DI + d];
        float dtx = dt * xv;
        float y = 0.f;
        #pragma unroll
        for (int s = 0; s < DS; ++s) {
            float e = __expf(dt * Ae[s]);
            h[s] = e * h[s] + dtx * Bsh[t][s];
            y += h[s] * Csh[t][s];
        }
        y += dpv * xv;
        float z = XZ[(size_t)l * (2 * DI) + DI + d];
        Gb[(size_t)l * DI + d] = f2bf(y * (z * sigm(z)));
    }
}

extern "C" void kernel_launch(void* const* d_in, const int* in_sizes, int n_in,
                              void* d_out, int out_size, void* d_ws, size_t ws_size,
                              hipStream_t stream)
{
    (void)in_sizes; (void)n_in; (void)out_size; (void)ws_size;
    const float* x = (const float*)d_in[0];
    const float* inW[2]  = {(const float*)d_in[1],  (const float*)d_in[11]};
    const float* inb[2]  = {(const float*)d_in[2],  (const float*)d_in[12]};
    const float* cw[2]   = {(const float*)d_in[3],  (const float*)d_in[13]};
    const float* cb[2]   = {(const float*)d_in[4],  (const float*)d_in[14]};
    const float* xpW[2]  = {(const float*)d_in[5],  (const float*)d_in[15]};
    const float* xpb[2]  = {(const float*)d_in[6],  (const float*)d_in[16]};
    const float* dtW[2]  = {(const float*)d_in[7],  (const float*)d_in[17]};
    const float* dtb[2]  = {(const float*)d_in[8],  (const float*)d_in[18]};
    const float* outW[2] = {(const float*)d_in[9],  (const float*)d_in[19]};
    const float* outb[2] = {(const float*)d_in[10], (const float*)d_in[20]};
    const float* Alog = (const float*)d_in[21];
    const float* Dp   = (const float*)d_in[22];
    const float* fuW  = (const float*)d_in[23];
    const float* fub  = (const float*)d_in[24];
    float* out = (float*)d_out;

    float* ws = (float*)d_ws;
    size_t off = 0;
    auto alloc = [&](size_t n) { float* p = ws + off; off += n; return p; };
    float* XZ  = alloc((size_t)2 * L_SEQ * 2 * DI);
    float* XC  = alloc((size_t)2 * L_SEQ * DI);
    float* SP  = alloc((size_t)2 * L_SEQ * NSP);
    float* DTb = alloc((size_t)2 * L_SEQ * DI);
    float* Pend= alloc((size_t)2 * NC * DI * DS);
    float* Hl  = alloc((size_t)2 * NC * DI * DS);
    float* Hs  = alloc((size_t)2 * NC * DI * DS);

    ushortT* wsu = (ushortT*)(ws + off);
    size_t uoff = 0;
    auto ualloc = [&](size_t n) { ushortT* p = wsu + uoff; uoff += n; return p; };
    ushortT* WtIn  = ualloc((size_t)2 * (2 * DI) * DM);
    ushortT* WtXp  = ualloc((size_t)2 * NSP * DI);
    ushortT* WtDt  = ualloc((size_t)2 * DI * DI);
    ushortT* WtOut = ualloc((size_t)2 * DM * DI);
    ushortT* WtFu  = ualloc((size_t)DM * DI);
    ushortT* XB    = ualloc((size_t)L_SEQ * DM);
    ushortT* SCb   = ualloc((size_t)2 * L_SEQ * DI);
    ushortT* SPb   = ualloc((size_t)2 * L_SEQ * DI);
    ushortT* Gb    = ualloc((size_t)2 * L_SEQ * DI);
    ushortT* OCb   = ualloc((size_t)L_SEQ * DI);

    dim3 blk(256);

    // 0) batched weight conversions (one dispatch) + x conversion
    WC wc;
    const float* srcs[9] = {inW[0], inW[1], xpW[0], xpW[1], dtW[0], dtW[1],
                            outW[0], outW[1], fuW};
    ushortT* dsts[9] = {WtIn, WtIn + (size_t)2 * DI * DM,
                        WtXp, WtXp + (size_t)NSP * DI,
                        WtDt, WtDt + (size_t)DI * DI,
                        WtOut, WtOut + (size_t)DM * DI,
                        WtFu};
    int Ks[9] = {DM, DM, DI, DI, DI, DI, DI, DI, DI};
    int Ns[9] = {2 * DI, 2 * DI, NSP, NSP, DI, DI, DM, DM, DM};
    wc.off[0] = 0;
    for (int m = 0; m < 9; ++m) {
        wc.src[m] = srcs[m]; wc.dst[m] = dsts[m];
        wc.K[m] = Ks[m]; wc.N[m] = Ns[m];
        wc.tN[m] = Ns[m] / 32;
        wc.off[m + 1] = wc.off[m] + (Ns[m] / 32) * (Ks[m] / 32);
    }
    wcvt_all<<<dim3(wc.off[9]), blk, 0, stream>>>(wc);
    xcvt_k<<<dim3(L_SEQ * DM / 1024), blk, 0, stream>>>(x, XB, L_SEQ * DM);

    // 1) input projection, both dirs (dir1 reads x reversed)
    gemm_bf16<128, 128><<<dim3(16, 16, 2), blk, 0, stream>>>(
        XB, DM, 0, 2, WtIn, (long long)2 * DI * DM, inb[0], inb[1],
        XZ, 2 * DI, (long long)L_SEQ * 2 * DI, nullptr, 0, 0, 0,
        0, L_SEQ, 2 * DI, DM, 0);
    // 2) causal depthwise conv + silu, both dirs
    conv_k<<<dim3(L_SEQ * DI / 256, 1, 2), blk, 0, stream>>>(
        XZ, cw[0], cw[1], cb[0], cb[1], XC, SCb);
    // 3) sp = silu(conv) @ xp_W + xp_b  (fp32 SP + bf16 delta shadow)
    gemm_bf16<128, 64><<<dim3((NSP + 63) / 64, 16, 2), blk, 0, stream>>>(
        SCb, DI, (long long)L_SEQ * DI, 0, WtXp, (long long)NSP * DI, xpb[0], xpb[1],
        SP, NSP, (long long)L_SEQ * NSP, SPb, DI, (long long)L_SEQ * DI, DI,
        0, L_SEQ, NSP, DI, 0);
    // 4) dt = softplus(delta @ dt_W + dt_b)
    gemm_bf16<128, 64><<<dim3(16, 16, 2), blk, 0, stream>>>(
        SPb, DI, (long long)L_SEQ * DI, 0, WtDt, (long long)DI * DI, dtb[0], dtb[1],
        DTb, DI, (long long)L_SEQ * DI, nullptr, 0, 0, 0,
        0, L_SEQ, DI, DI, 1);
    // 5) chunked selective scan
    scanA_k<<<dim3(DI / 256, NC, 2), blk, 0, stream>>>(DTb, XC, SP, Alog, Pend, Hl);
    scanB_k<<<dim3(2 * DI * DS / 256), blk, 0, stream>>>(Pend, Hl, Hs);
    scanC_k<<<dim3(DI / 256, NC, 2), blk, 0, stream>>>(DTb, XC, SP, XZ, Alog, Dp, Hs, Gb);
    // 6) out projection -> bf16 concat buffer (dir1 rows reversed back, cols offset DM)
    gemm_bf16<64, 64><<<dim3(8, 32, 2), blk, 0, stream>>>(
        Gb, DI, (long long)L_SEQ * DI, 0, WtOut, (long long)DM * DI, outb[0], outb[1],
        nullptr, 0, 0, OCb, DI, (long long)DM, DM,
        2, L_SEQ, DM, DI, 0);
    // 7) fusion GEMM -> final output
    gemm_bf16<64, 64><<<dim3(8, 32, 1), blk, 0, stream>>>(
        OCb, DI, 0, 0, WtFu, 0, fub, fub,
        out, DM, (long long)0, nullptr, 0, 0, 0,
        0, L_SEQ, DM, DI, 0);
}